// Round 3
// baseline (1339.679 us; speedup 1.0000x reference)
//
#include <hip/hip_runtime.h>
#include <hip/hip_bf16.h>
#include <math.h>

// LineRWKVBlock: y = (x + sigmoid(x@Wr) * scan(x@Wv)) ; y += y@Wc
// B=16, W=2048, D=1024, decay=0.99.
//
// R3 structure:
//  1. prep_x8:      X fp32 -> fp8 e4m3 Xq (scale 1.0)
//  2. prep_weights: Wv,Wr -> fp8 x16 transposed Wq8; Wc -> bf16 transposed WcT
//  3. gemm_vr:      MX-fp8 mfma_scale_f32_16x16x128_f8f6f4, BK=128,
//                   uniform scales A=2^0 B=2^-4, XOR-swizzled LDS (16B blocks)
//  4. scan_partial: chunk-local decayed sums (ushort4 loads)
//  5. scan_chunk:   16-step chunk scan
//  6. scan_apply:   y_tmp = x + r*s  (in place over V, 4-wide)
//  7. gemm_mix:     y = y_tmp + y_tmp@Wc  (bf16 MFMA — fp8 would breach absmax)
//
// ws: Wq8 2 MiB | WcT 2 | Xq 32 | V/y_tmp 64 | R 64 | sl 1 | sin 1 = 166 MiB

#define MROWS 32768           // B*W
#define NCHUNK 16
#define CHUNKL 128
#define DECAY_F 0.99f
#define OM_F 0.01f

typedef __attribute__((ext_vector_type(8))) short short8;   // 8 bf16
typedef __attribute__((ext_vector_type(4))) float floatx4;
typedef __attribute__((ext_vector_type(8))) int i32x8;      // fp8 frag: 32 bytes

using bf16 = __hip_bfloat16;

__device__ __forceinline__ void async_copy16(const void* g, void* l) {
  __builtin_amdgcn_global_load_lds(
      (const __attribute__((address_space(1))) unsigned int*)g,
      (__attribute__((address_space(3))) unsigned int*)l, 16, 0, 0);
}

__device__ __forceinline__ float b2f(unsigned short u) {
  union { unsigned int i; float f; } t; t.i = ((unsigned int)u) << 16; return t.f;
}
__device__ __forceinline__ unsigned short f2bu(float f) {
  bf16 h = __float2bfloat16(f);
  return *reinterpret_cast<unsigned short*>(&h);
}

// ---------------- kernel 1: x fp32 -> fp8 e4m3 (8 elems/thread) -----------
__global__ void prep_x8(const float* __restrict__ X, unsigned char* __restrict__ Xq) {
  const int idx = blockIdx.x * 256 + threadIdx.x;      // 4194304
  const float4 v0 = ((const float4*)X)[idx * 2];
  const float4 v1 = ((const float4*)X)[idx * 2 + 1];
  int p0 = __builtin_amdgcn_cvt_pk_fp8_f32(v0.x, v0.y, 0, false);
  p0 = __builtin_amdgcn_cvt_pk_fp8_f32(v0.z, v0.w, p0, true);
  int p1 = __builtin_amdgcn_cvt_pk_fp8_f32(v1.x, v1.y, 0, false);
  p1 = __builtin_amdgcn_cvt_pk_fp8_f32(v1.z, v1.w, p1, true);
  ((uint2*)Xq)[idx] = make_uint2((unsigned)p0, (unsigned)p1);
}

// ---------------- kernel 2: weight transpose + quantize -------------------
// Wq8 rows 0..1023 = (16*Wv)^T fp8, 1024..2047 = (16*Wr)^T fp8; WcT = Wc^T bf16
__global__ void prep_weights(const float* __restrict__ Wv,
                             const float* __restrict__ Wr,
                             const float* __restrict__ Wc,
                             unsigned char* __restrict__ Wq8,
                             bf16* __restrict__ WcT) {
  __shared__ float tile[32][33];
  const int bk = blockIdx.x * 32;   // k block
  const int bn = blockIdx.y * 32;   // global n block (0..3071)
  const float* src;
  int nbase = bn;
  if (bn < 1024)      { src = Wv; }
  else if (bn < 2048) { src = Wr; nbase = bn - 1024; }
  else                { src = Wc; nbase = bn - 2048; }
  const int tx = threadIdx.x;       // 32
  const int ty = threadIdx.y;       // 8
  #pragma unroll
  for (int i = ty; i < 32; i += 8)
    tile[i][tx] = src[(size_t)(bk + i) * 1024 + nbase + tx];  // tile[k][n]
  __syncthreads();
  if (bn < 2048) {
    #pragma unroll
    for (int i = ty; i < 32; i += 8) {
      const int p = __builtin_amdgcn_cvt_pk_fp8_f32(tile[tx][i] * 16.0f, 0.f, 0, false);
      Wq8[(size_t)(bn + i) * 1024 + bk + tx] = (unsigned char)(p & 0xff);
    }
  } else {
    #pragma unroll
    for (int i = ty; i < 32; i += 8)
      WcT[(size_t)(bn - 2048 + i) * 1024 + bk + tx] = __float2bfloat16(tile[tx][i]);
  }
}

// ---------------- kernel 3: fused v/r GEMM, MX-fp8 K=128 ------------------
// Xq fp8 [M][1024]; Wq8 fp8 [2048][1024] (x16); nt 0..7 -> v, 8..15 -> r
__global__ __launch_bounds__(256, 3) void gemm_vr(const unsigned char* __restrict__ Xq,
                                                  const unsigned char* __restrict__ Wq8,
                                                  bf16* __restrict__ Vout,
                                                  bf16* __restrict__ Rout) {
  __shared__ uint4 As4[1024];   // 128 rows x 128 B (8 x 16B blocks, XOR-swizzled)
  __shared__ uint4 Bs4[1024];
  const int t = threadIdx.x;
  const int id = blockIdx.x;                 // 4096 = 16 nt * 256 mt
  const int grp = id >> 3, xcd = id & 7;
  const int mt = ((grp >> 4) << 3) | xcd;
  const int nt = grp & 15;
  const int m0 = mt * 128;
  const int lane = t & 63, wave = t >> 6;
  const int wm = (wave >> 1) * 64, wn = (wave & 1) * 64;
  const int ln15 = lane & 15, qd = lane >> 4;
  const int swz = ln15 & 7;

  const unsigned char* Asrc = Xq + (size_t)m0 * 1024;
  const unsigned char* Bsrc = Wq8 + (size_t)(nt * 128) * 1024;

  // staging: lane i covers row r8=i>>3, 16B block i&7; global col XORed so
  // LDS block (row, pb) holds logical block pb ^ (row&7) (self-inverse).
  const int r8 = lane >> 3;
  const int xcol = ((lane & 7) ^ r8) * 16;

  floatx4 acc[4][4];
  #pragma unroll
  for (int i = 0; i < 4; ++i)
    #pragma unroll
    for (int j = 0; j < 4; ++j) acc[i][j] = (floatx4){0.f, 0.f, 0.f, 0.f};

  for (int k0 = 0; k0 < 1024; k0 += 128) {
    #pragma unroll
    for (int c = 0; c < 4; ++c) {
      const int rbase = wave * 32 + c * 8;                 // 8 rows per call
      const size_t goff = (size_t)(rbase + r8) * 1024 + k0 + xcol;
      async_copy16(Asrc + goff, (char*)&As4[rbase * 8]);
      async_copy16(Bsrc + goff, (char*)&Bs4[rbase * 8]);
    }
    __syncthreads();
    i32x8 fa[4], fb[4];
    #pragma unroll
    for (int tm = 0; tm < 4; ++tm) {
      const int row = wm + tm * 16 + ln15;                 // row&7 == swz
      const uint4 lo = As4[row * 8 + ((qd * 2) ^ swz)];
      const uint4 hi = As4[row * 8 + ((qd * 2 + 1) ^ swz)];
      fa[tm][0] = lo.x; fa[tm][1] = lo.y; fa[tm][2] = lo.z; fa[tm][3] = lo.w;
      fa[tm][4] = hi.x; fa[tm][5] = hi.y; fa[tm][6] = hi.z; fa[tm][7] = hi.w;
    }
    #pragma unroll
    for (int tn = 0; tn < 4; ++tn) {
      const int row = wn + tn * 16 + ln15;
      const uint4 lo = Bs4[row * 8 + ((qd * 2) ^ swz)];
      const uint4 hi = Bs4[row * 8 + ((qd * 2 + 1) ^ swz)];
      fb[tn][0] = lo.x; fb[tn][1] = lo.y; fb[tn][2] = lo.z; fb[tn][3] = lo.w;
      fb[tn][4] = hi.x; fb[tn][5] = hi.y; fb[tn][6] = hi.z; fb[tn][7] = hi.w;
    }
    #pragma unroll
    for (int tm = 0; tm < 4; ++tm)
      #pragma unroll
      for (int tn = 0; tn < 4; ++tn)
        // uniform scales: A = 2^0 (127), B = 2^-4 (123; weights pre-scaled x16)
        acc[tm][tn] = __builtin_amdgcn_mfma_scale_f32_16x16x128_f8f6f4(
            fa[tm], fb[tn], acc[tm][tn], 0, 0, 0, 127, 0, 123);
    __syncthreads();
  }

  const bool isr = (nt >= 8);
  bf16* outp = isr ? Rout : Vout;
  const int nc0 = (nt & 7) * 128;
  #pragma unroll
  for (int tm = 0; tm < 4; ++tm) {
    #pragma unroll
    for (int i = 0; i < 4; ++i) {
      const int m_g = m0 + wm + tm * 16 + qd * 4 + i;   // C/D: row = quad*4+reg
      const size_t rowoff = (size_t)m_g * 1024 + nc0;
      #pragma unroll
      for (int tn = 0; tn < 4; ++tn) {
        float cv = acc[tm][tn][i];
        if (isr) cv = 1.0f / (1.0f + __expf(-cv));
        outp[rowoff + wn + tn * 16 + ln15] = __float2bfloat16(cv);
      }
    }
  }
}

// ---------------- kernel 4: chunk-local decayed sums (4-wide) -------------
__global__ void scan_partial(const bf16* __restrict__ V, float* __restrict__ sl) {
  const int idx = blockIdx.x * 256 + threadIdx.x;   // 65536 = B*NCHUNK*(D/4)
  const int d4 = idx & 255;
  const int c = (idx >> 8) & 15;
  const int b = idx >> 12;
  const ushort4* V4 = (const ushort4*)V;
  const size_t base = (size_t)(b * 2048 + c * 128) * 256 + d4;
  float s0 = 0.f, s1 = 0.f, s2 = 0.f, s3 = 0.f;
  for (int w = 0; w < CHUNKL; ++w) {
    const ushort4 v = V4[base + (size_t)w * 256];
    s0 = DECAY_F * s0 + OM_F * b2f(v.x);
    s1 = DECAY_F * s1 + OM_F * b2f(v.y);
    s2 = DECAY_F * s2 + OM_F * b2f(v.z);
    s3 = DECAY_F * s3 + OM_F * b2f(v.w);
  }
  ((float4*)sl)[(b * 16 + c) * 256 + d4] = make_float4(s0, s1, s2, s3);
}

// ---------------- kernel 5: chunk-level scan ----------------
__global__ void scan_chunk(const float* __restrict__ state,
                           const float* __restrict__ sl,
                           float* __restrict__ sin_,
                           float* __restrict__ state_out,
                           float decayL) {
  const int idx = blockIdx.x * 256 + threadIdx.x;   // 16384 = B*D
  const int d = idx & 1023;
  const int b = idx >> 10;
  float s = state[idx];
  #pragma unroll
  for (int c = 0; c < NCHUNK; ++c) {
    const int o = (b * 16 + c) * 1024 + d;
    sin_[o] = s;
    s = decayL * s + sl[o];
  }
  state_out[idx] = s;
}

// ---------------- kernel 6: y_tmp = x + r*s (in place over V, 4-wide) -----
__global__ void scan_apply(const float* __restrict__ X,
                           const bf16* __restrict__ R,
                           const float* __restrict__ sin_,
                           bf16* __restrict__ VY) {
  const int idx = blockIdx.x * 256 + threadIdx.x;   // 65536
  const int d4 = idx & 255;
  const int c = (idx >> 8) & 15;
  const int b = idx >> 12;
  const ushort4* R4 = (const ushort4*)R;
  const float4* X4 = (const float4*)X;
  ushort4* VY4 = (ushort4*)VY;
  const size_t base = (size_t)(b * 2048 + c * 128) * 256 + d4;
  float4 s = ((const float4*)sin_)[(b * 16 + c) * 256 + d4];
  for (int w = 0; w < CHUNKL; ++w) {
    const size_t off = base + (size_t)w * 256;
    const ushort4 v = VY4[off];
    const ushort4 r = R4[off];
    const float4 xx = X4[off];
    s.x = DECAY_F * s.x + OM_F * b2f(v.x);
    s.y = DECAY_F * s.y + OM_F * b2f(v.y);
    s.z = DECAY_F * s.z + OM_F * b2f(v.z);
    s.w = DECAY_F * s.w + OM_F * b2f(v.w);
    ushort4 o;
    o.x = f2bu(xx.x + b2f(r.x) * s.x);
    o.y = f2bu(xx.y + b2f(r.y) * s.y);
    o.z = f2bu(xx.z + b2f(r.z) * s.z);
    o.w = f2bu(xx.w + b2f(r.w) * s.w);
    VY4[off] = o;
  }
}

// ---------------- kernel 7: y = y_tmp + y_tmp @ Wc (bf16, unchanged) ------
__global__ __launch_bounds__(256, 3) void gemm_mix(const bf16* __restrict__ Yt,
                                                   const bf16* __restrict__ WcT,
                                                   float* __restrict__ Out) {
  __shared__ bf16 As[128][32];
  __shared__ bf16 Bs[128][32];
  const int t = threadIdx.x;
  const int id = blockIdx.x;                 // 2048 = 8 nt * 256 mt
  const int grp = id >> 3, xcd = id & 7;
  const int mt = ((grp >> 3) << 3) | xcd;
  const int nt = grp & 7;
  const int m0 = mt * 128;
  const int nc0 = nt * 128;
  const int lane = t & 63, wave = t >> 6;
  const int wm = wave >> 1, wn = wave & 1;
  const int ln15 = lane & 15, qd = lane >> 4;

  const bf16* Asrc = Yt + (size_t)m0 * 1024;
  const bf16* Bsrc = WcT + (size_t)nc0 * 1024;

  const int srow = lane >> 2;
  const int skb  = (lane & 3) * 8;

  floatx4 acc[4][4];
  #pragma unroll
  for (int i = 0; i < 4; ++i)
    #pragma unroll
    for (int j = 0; j < 4; ++j) acc[i][j] = (floatx4){0.f, 0.f, 0.f, 0.f};

  for (int k0 = 0; k0 < 1024; k0 += 32) {
    #pragma unroll
    for (int s = 0; s < 2; ++s) {
      const int seg = wave * 2 + s;
      const size_t roff = (size_t)(seg * 16 + srow) * 1024 + k0 + skb;
      async_copy16(&Asrc[roff], &As[seg * 16][0]);
      async_copy16(&Bsrc[roff], &Bs[seg * 16][0]);
    }
    __syncthreads();
    short8 fa[4], fb[4];
    #pragma unroll
    for (int tm = 0; tm < 4; ++tm)
      fa[tm] = *(const short8*)&As[wm * 64 + tm * 16 + ln15][qd * 8];
    #pragma unroll
    for (int tn = 0; tn < 4; ++tn)
      fb[tn] = *(const short8*)&Bs[wn * 64 + tn * 16 + ln15][qd * 8];
    #pragma unroll
    for (int tm = 0; tm < 4; ++tm)
      #pragma unroll
      for (int tn = 0; tn < 4; ++tn)
        acc[tm][tn] = __builtin_amdgcn_mfma_f32_16x16x32_bf16(
            fa[tm], fb[tn], acc[tm][tn], 0, 0, 0);
    __syncthreads();
  }

  #pragma unroll
  for (int tm = 0; tm < 4; ++tm) {
    #pragma unroll
    for (int i = 0; i < 4; ++i) {
      const int m_g = m0 + wm * 64 + tm * 16 + qd * 4 + i;
      const size_t rowoff = (size_t)m_g * 1024 + nc0;
      #pragma unroll
      for (int tn = 0; tn < 4; ++tn) {
        const size_t o = rowoff + wn * 64 + tn * 16 + ln15;
        Out[o] = b2f(*(const unsigned short*)&Yt[o]) + acc[tm][tn][i];
      }
    }
  }
}

extern "C" void kernel_launch(void* const* d_in, const int* in_sizes, int n_in,
                              void* d_out, int out_size, void* d_ws, size_t ws_size,
                              hipStream_t stream) {
  const float* x     = (const float*)d_in[0];
  const float* state = (const float*)d_in[1];
  const float* Wv    = (const float*)d_in[2];
  const float* Wr    = (const float*)d_in[3];
  const float* Wc    = (const float*)d_in[4];

  float* y_out = (float*)d_out;
  float* state_out = y_out + (size_t)MROWS * 1024;

  char* ws = (char*)d_ws;
  unsigned char* Wq8 = (unsigned char*)ws;                   // 2 MiB
  bf16* WcT  = (bf16*)(ws + ((size_t)2 << 20));              // 2 MiB
  unsigned char* Xq  = (unsigned char*)(ws + ((size_t)4 << 20));  // 32 MiB
  bf16* Vbuf = (bf16*)(ws + ((size_t)36 << 20));             // 64 MiB (also y_tmp)
  bf16* Rbuf = (bf16*)(ws + ((size_t)100 << 20));            // 64 MiB
  float* sl  = (float*)(ws + ((size_t)164 << 20));           // 1 MiB
  float* sin_ = (float*)(ws + ((size_t)165 << 20));          // 1 MiB

  const float decayL = (float)pow(0.99, (double)CHUNKL);

  prep_x8<<<16384, 256, 0, stream>>>(x, Xq);
  prep_weights<<<dim3(32, 96), dim3(32, 8), 0, stream>>>(Wv, Wr, Wc, Wq8, WcT);
  gemm_vr<<<4096, 256, 0, stream>>>(Xq, Wq8, Vbuf, Rbuf);
  scan_partial<<<256, 256, 0, stream>>>(Vbuf, sl);
  scan_chunk<<<64, 256, 0, stream>>>(state, sl, sin_, state_out, decayL);
  scan_apply<<<256, 256, 0, stream>>>(x, Rbuf, sin_, Vbuf);
  gemm_mix<<<2048, 256, 0, stream>>>(Vbuf, WcT, y_out);
}